// Round 1
// baseline (713.742 us; speedup 1.0000x reference)
//
#include <hip/hip_runtime.h>
#include <math.h>

typedef __attribute__((ext_vector_type(8))) __bf16 bf16x8;
typedef __attribute__((ext_vector_type(4))) float fx4;

__device__ __forceinline__ unsigned short f2bf(float f) {
  union { float f; unsigned int u; } v; v.f = f;
  unsigned int r = v.u + 0x7fffu + ((v.u >> 16) & 1u);
  return (unsigned short)(r >> 16);
}
__device__ __forceinline__ float bf2f(unsigned short b) {
  union { unsigned int u; float f; } v; v.u = ((unsigned int)b) << 16;
  return v.f;
}

// async global->LDS, 16B per lane. LDS dest must be wave-uniform base + lane*16;
// every call site's LDS expression reduces to (16*tid + uniform).
__device__ __forceinline__ void gll16(const unsigned short* g, unsigned short* l) {
  __builtin_amdgcn_global_load_lds(
      (const __attribute__((address_space(1))) unsigned int*)g,
      (__attribute__((address_space(3))) unsigned int*)l, 16, 0, 0);
}

// ---------------- fp32 -> bf16 elementwise ----------------
__global__ void cvt_f32_bf16(const float* __restrict__ in, unsigned short* __restrict__ out, long n) {
  long i = ((long)blockIdx.x * blockDim.x + threadIdx.x) * 4;
  if (i + 3 >= n) {
    for (long j = i; j < n; j++) out[j] = f2bf(in[j]);
    return;
  }
  float4 v = *reinterpret_cast<const float4*>(in + i);
  ushort4 o;
  o.x = f2bf(v.x); o.y = f2bf(v.y); o.z = f2bf(v.z); o.w = f2bf(v.w);
  *reinterpret_cast<ushort4*>(out + i) = o;
}

// ---------------- transpose + convert: fp32 [R][C] -> bf16 [C][R] ----------------
__global__ void transpose_cvt(const float* __restrict__ in, unsigned short* __restrict__ out,
                              int R, int C) {
  __shared__ float tile[32][33];
  const int c0 = blockIdx.x * 32, r0 = blockIdx.y * 32;
  const int tx = threadIdx.x, ty = threadIdx.y;  // block (32,8)
#pragma unroll
  for (int k = 0; k < 32; k += 8) {
    int r = r0 + ty + k, c = c0 + tx;
    tile[ty + k][tx] = (r < R && c < C) ? in[(long)r * C + c] : 0.f;
  }
  __syncthreads();
#pragma unroll
  for (int k = 0; k < 32; k += 8) {
    int orow = c0 + ty + k;
    int oc = r0 + tx;
    if (orow < C && oc < R) out[(long)orow * R + oc] = f2bf(tile[tx][ty + k]);
  }
}

// ---------------- bf16 MFMA GEMM: C[M][N] = A[M][K] * Bt[N][K]^T ----------------
// 128x128 tile, BK=64, gll16 staging with XOR chunk swizzle (LDS slot c of
// row r holds global chunk c^(r&7)). 2-PHASE double-buffered pipeline:
// STAGE(next K-tile) is issued BEFORE compute(current); the vmcnt(0) drain
// (inside __syncthreads) lands AFTER ~32 MFMAs instead of right after issue,
// so global->LDS latency hides under compute. One barrier per K-step.
// K must be a multiple of 128 (all call sites: 2048/4096).
// SPLIT: cols < splitN -> C0 [m][n] bf16, cols >= splitN -> C1 transposed
// [n-splitN][m] bf16.
template <int OUT_BF16, int SPLIT, int BIAS>
__global__ __launch_bounds__(256) void gemm_bt(
    const unsigned short* __restrict__ A,   // [M][*lda] bf16
    const unsigned short* __restrict__ Bt,  // [N][*ldb] bf16
    void* __restrict__ C0, void* __restrict__ C1,
    const float* __restrict__ bias,
    int M, int N, int K, int lda, int ldb, int ldc0, int splitN, int ldc1) {
  __shared__ unsigned short As[2][128 * 64];
  __shared__ unsigned short Bs[2][128 * 64];

  const int tid = threadIdx.x;
  const int bn = blockIdx.x * 128;
  const int bm = blockIdx.y * 128;
  const int wave = tid >> 6;
  const int lane = tid & 63;
  const int wm = (wave >> 1) * 64;
  const int wn = (wave & 1) * 64;
  const int lrow = lane & 15;
  const int quad = lane >> 4;

  fx4 acc[4][4];
  const fx4 zero = {0.f, 0.f, 0.f, 0.f};
#pragma unroll
  for (int i = 0; i < 4; i++)
#pragma unroll
    for (int j = 0; j < 4; j++) acc[i][j] = zero;

  const int srow = tid >> 3;                      // 0..31 (LDS row base; +32p)
  const int sw = ((tid & 7) ^ (srow & 7)) * 8;    // swizzled global k-offset

  const unsigned short* ap[4];
  const unsigned short* bp[4];
  int soff[4];                                    // LDS short-offset per p
#pragma unroll
  for (int p = 0; p < 4; p++) {
    const int row = srow + 32 * p;
    ap[p] = A + (long)(bm + row) * lda + sw;
    int nb = bn + row; if (nb > N - 1) nb = N - 1;  // clamp partial-N (epilogue guards)
    bp[p] = Bt + (long)nb * ldb + sw;
    soff[p] = row * 64 + (tid & 7) * 8;
  }

  auto stage = [&](int buf, int k0) {
#pragma unroll
    for (int p = 0; p < 4; p++) gll16(ap[p] + k0, &As[buf][soff[p]]);
#pragma unroll
    for (int p = 0; p < 4; p++) gll16(bp[p] + k0, &Bs[buf][soff[p]]);
  };

  auto compute = [&](int buf) {
#pragma unroll
    for (int kd = 0; kd < 2; kd++) {
      const int co = ((kd * 4 + quad) ^ (lrow & 7)) * 8;  // un-swizzled chunk
      bf16x8 af[4], bfr[4];
#pragma unroll
      for (int i = 0; i < 4; i++)
        af[i] = *reinterpret_cast<const bf16x8*>(&As[buf][(wm + i * 16 + lrow) * 64 + co]);
#pragma unroll
      for (int j = 0; j < 4; j++)
        bfr[j] = *reinterpret_cast<const bf16x8*>(&Bs[buf][(wn + j * 16 + lrow) * 64 + co]);
#pragma unroll
      for (int i = 0; i < 4; i++)
#pragma unroll
        for (int j = 0; j < 4; j++)
          acc[i][j] = __builtin_amdgcn_mfma_f32_16x16x32_bf16(af[i], bfr[j], acc[i][j], 0, 0, 0);
    }
  };

  // prologue: stage tile 0 into buf0, drain, then 2-phase main loop
  stage(0, 0);
  __syncthreads();
  for (int k0 = 0; k0 < K; k0 += 128) {
    stage(1, k0 + 64);          // prefetch tile k0+64 while computing k0
    compute(0);
    __syncthreads();            // vmcnt(0) drain AFTER compute + barrier
    if (k0 + 128 < K) stage(0, k0 + 128);
    compute(1);
    __syncthreads();
  }

  // C row = quad*4+reg, col = lane&15
#pragma unroll
  for (int i = 0; i < 4; i++) {
#pragma unroll
    for (int j = 0; j < 4; j++) {
      const int gn = bn + wn + j * 16 + lrow;
      if (gn < N) {
        const int gmb = bm + wm + i * 16 + quad * 4;
        if (SPLIT && gn >= splitN) {
#pragma unroll
          for (int r = 0; r < 4; r++)
            ((unsigned short*)C1)[(long)(gn - splitN) * ldc1 + gmb + r] = f2bf(acc[i][j][r]);
        } else {
          float bv = 0.f;
          if (BIAS) bv = bias[gn];
#pragma unroll
          for (int r = 0; r < 4; r++) {
            float v = acc[i][j][r] + bv;
            long idx = (long)(gmb + r) * ldc0 + gn;
            if (OUT_BF16) ((unsigned short*)C0)[idx] = f2bf(v);
            else ((float*)C0)[idx] = v;
          }
        }
      }
    }
  }
}

// ---------------- RoPE ----------------
__global__ void rope_q_kernel(unsigned short* __restrict__ q, const int* __restrict__ past_p, int S) {
  int idx = blockIdx.x * blockDim.x + threadIdx.x;
  if (idx >= S * 32 * 32) return;
  int i = idx & 31, h = (idx >> 5) & 31, s = idx >> 10;
  int past = past_p[0];
  float f = powf(10000.0f, -(float)i * (1.0f / 64.0f));
  float ang = (float)(past + s) * f;
  float sn, cs;
  sincosf(ang, &sn, &cs);
  unsigned short* base = q + (long)s * 4096 + h * 128 + 64;
  float x1 = bf2f(base[i]), x2 = bf2f(base[i + 32]);
  base[i] = f2bf(x1 * cs - x2 * sn);
  base[i + 32] = f2bf(x2 * cs + x1 * sn);
}

__global__ void rope_k_kernel(unsigned short* __restrict__ kr, const int* __restrict__ past_p,
                              int S, int ldk) {
  int idx = blockIdx.x * blockDim.x + threadIdx.x;
  if (idx >= S * 32) return;
  int i = idx & 31, s = idx >> 5;
  int past = past_p[0];
  float f = powf(10000.0f, -(float)i * (1.0f / 64.0f));
  float ang = (float)(past + s) * f;
  float sn, cs;
  sincosf(ang, &sn, &cs);
  unsigned short* base = kr + (long)s * ldk;
  float x1 = bf2f(base[i]), x2 = bf2f(base[i + 32]);
  base[i] = f2bf(x1 * cs - x2 * sn);
  base[i + 32] = f2bf(x2 * cs + x1 * sn);
}

// ---------------- flash attention (no-max softmax, deferred l-reduction) ----
// block = 1 head x 128 q-rows; 4 waves x 32 q-rows; 64-key tiles.
// Ks/Vs staged via gll16 with XOR chunk swizzle to kill the stride-degenerate
// bank conflicts.
__global__ __launch_bounds__(256, 2) void attn_kernel(
    const unsigned short* __restrict__ Q,   // [S][4096] bf16 (rope applied)
    const unsigned short* __restrict__ Kn,  // [S][2048] bf16
    const unsigned short* __restrict__ Kr,  // [S][ldkr] bf16 (rope applied)
    const unsigned short* __restrict__ Vt,  // [4096][S] bf16 (per-head transposed)
    unsigned short* __restrict__ O,         // [S][4096] bf16
    int S, int ldkr) {
  const int h = blockIdx.y;
  const int sb = blockIdx.x * 128;
  const int tid = threadIdx.x;
  const int wave = tid >> 6;
  const int lane = tid & 63;
  const int lrow = lane & 15;
  const int quad = lane >> 4;

  __shared__ unsigned short Ks[64 * 128];   // [key][d], chunk-swizzled by key&15
  __shared__ unsigned short Vs[128 * 64];   // [dv][key], chunk-swizzled by dv&7
  __shared__ unsigned short Ps[4][32 * 72]; // per-wave P tile

  const int qr0 = sb + wave * 32;

  bf16x8 qf[2][4];
#pragma unroll
  for (int qi = 0; qi < 2; qi++)
#pragma unroll
    for (int kd = 0; kd < 4; kd++)
      qf[qi][kd] = *reinterpret_cast<const bf16x8*>(
          Q + (long)(qr0 + qi * 16 + lrow) * 4096 + h * 128 + kd * 32 + quad * 8);

  fx4 accO[2][8];
  const fx4 zero = {0.f, 0.f, 0.f, 0.f};
#pragma unroll
  for (int qi = 0; qi < 2; qi++)
#pragma unroll
    for (int t = 0; t < 8; t++) accO[qi][t] = zero;
  float lsum[2][4] = {{0.f, 0.f, 0.f, 0.f}, {0.f, 0.f, 0.f, 0.f}};
  const float scale = 0.08838834764831845f;  // 1/sqrt(128)

  // K staging: LDS row kkey+16p, slot chunk tid&15 holds global chunk cgk
  const int kkey = tid >> 4;                     // 0..15
  const int cgk = ((tid & 15) ^ kkey) * 8;       // swizzled global d-offset 0..120
  // V staging: LDS row vdv+32p, slot chunk tid&7 holds global chunk cgv
  const int vdv = tid >> 3;                      // 0..31
  const int cgv = ((tid & 7) ^ (vdv & 7)) * 8;   // swizzled global key-offset 0..56

  for (int kb = 0; kb < S; kb += 64) {
    __syncthreads();
#pragma unroll
    for (int p = 0; p < 4; p++) {
      const int key = kb + kkey + 16 * p;
      const unsigned short* gn_ = Kn + (long)key * 2048 + h * 64 + cgk;
      const unsigned short* gr_ = Kr + (long)key * ldkr + (cgk - 64);
      gll16(cgk < 64 ? gn_ : gr_, &Ks[(kkey + 16 * p) * 128 + (tid & 15) * 8]);
    }
#pragma unroll
    for (int p = 0; p < 4; p++)
      gll16(Vt + (long)(h * 128 + vdv + 32 * p) * S + kb + cgv,
            &Vs[(vdv + 32 * p) * 64 + (tid & 7) * 8]);
    __syncthreads();

    // QK^T: 2 q-subtiles x 64 keys (Ks chunk un-swizzle: c=(kd*4+quad)^lrow)
    fx4 c[2][4];
#pragma unroll
    for (int qi = 0; qi < 2; qi++)
#pragma unroll
      for (int ks2 = 0; ks2 < 4; ks2++) c[qi][ks2] = zero;
#pragma unroll
    for (int ks2 = 0; ks2 < 4; ks2++) {
#pragma unroll
      for (int kd = 0; kd < 4; kd++) {
        bf16x8 kf = *reinterpret_cast<const bf16x8*>(
            &Ks[(ks2 * 16 + lrow) * 128 + (((kd * 4 + quad) ^ lrow) * 8)]);
        c[0][ks2] = __builtin_amdgcn_mfma_f32_16x16x32_bf16(qf[0][kd], kf, c[0][ks2], 0, 0, 0);
        c[1][ks2] = __builtin_amdgcn_mfma_f32_16x16x32_bf16(qf[1][kd], kf, c[1][ks2], 0, 0, 0);
      }
    }

    // exp + per-lane l accumulation + P store (C-layout row=quad*4+r, col=16*ks2+lrow)
#pragma unroll
    for (int qi = 0; qi < 2; qi++) {
#pragma unroll
      for (int ks2 = 0; ks2 < 4; ks2++) {
#pragma unroll
        for (int r = 0; r < 4; r++) {
          float p = __expf(c[qi][ks2][r] * scale);
          lsum[qi][r] += p;
          Ps[wave][(qi * 16 + quad * 4 + r) * 72 + ks2 * 16 + lrow] = f2bf(p);
        }
      }
    }
    __threadfence_block();  // order cross-lane LDS write->read within the wave

    // PV: P (A-layout) x V^T (B-layout; Vs chunk un-swizzle c=(kc*4+quad)^(lrow&7))
#pragma unroll
    for (int kc = 0; kc < 2; kc++) {
      bf16x8 pf0 = *reinterpret_cast<const bf16x8*>(&Ps[wave][lrow * 72 + kc * 32 + quad * 8]);
      bf16x8 pf1 = *reinterpret_cast<const bf16x8*>(&Ps[wave][(16 + lrow) * 72 + kc * 32 + quad * 8]);
      const int vco = (((kc * 4 + quad) ^ (lrow & 7)) * 8);
#pragma unroll
      for (int t = 0; t < 8; t++) {
        bf16x8 vf = *reinterpret_cast<const bf16x8*>(&Vs[(t * 16 + lrow) * 64 + vco]);
        accO[0][t] = __builtin_amdgcn_mfma_f32_16x16x32_bf16(pf0, vf, accO[0][t], 0, 0, 0);
        accO[1][t] = __builtin_amdgcn_mfma_f32_16x16x32_bf16(pf1, vf, accO[1][t], 0, 0, 0);
      }
    }
  }

  // one-time l reduction across the 16 lanes of each quad, then normalize+store
  float linv[2][4];
#pragma unroll
  for (int qi = 0; qi < 2; qi++)
#pragma unroll
    for (int r = 0; r < 4; r++) {
      float l = lsum[qi][r];
#pragma unroll
      for (int off = 8; off; off >>= 1) l += __shfl_xor(l, off, 16);
      linv[qi][r] = 1.0f / l;
    }
#pragma unroll
  for (int qi = 0; qi < 2; qi++)
#pragma unroll
    for (int t = 0; t < 8; t++)
#pragma unroll
      for (int r = 0; r < 4; r++) {
        float v = accO[qi][t][r] * linv[qi][r];
        int row = qr0 + qi * 16 + quad * 4 + r;
        O[(long)row * 4096 + h * 128 + t * 16 + lrow] = f2bf(v);
      }
}

// ---------------- launch ----------------
extern "C" void kernel_launch(void* const* d_in, const int* in_sizes, int n_in,
                              void* d_out, int out_size, void* d_ws, size_t ws_size,
                              hipStream_t stream) {
  (void)in_sizes; (void)n_in; (void)out_size; (void)ws_size;
  const float* x     = (const float*)d_in[0];
  const float* W_DQ  = (const float*)d_in[1];
  const float* W_UQ  = (const float*)d_in[2];
  const float* W_DKV = (const float*)d_in[3];
  const float* W_UK  = (const float*)d_in[4];
  const float* W_UV  = (const float*)d_in[5];
  const float* W_Kr  = (const float*)d_in[6];
  const float* W_O   = (const float*)d_in[7];
  const float* b_O   = (const float*)d_in[8];
  const int* past    = (const int*)d_in[9];
  float* out = (float*)d_out;

  const int S = 2048, D = 4096, P = 2048;
  const int NA = P + P + 64;  // 4160: fused [W_DQ|W_DKV|W_Kr] output width
  char* ws = (char*)d_ws;
  const long MB = 1024 * 1024;
  unsigned short* xb    = (unsigned short*)(ws);            // 16 MB [S][D] x / attn-out
  unsigned short* wt    = (unsigned short*)(ws + 16 * MB);  // ~34 MB transposed weights (reused)
  unsigned short* qb    = (unsigned short*)(ws + 36 * MB);  // 16 MB q
  unsigned short* cqkv  = (unsigned short*)(ws + 52 * MB);  // 17.1 MB [S][4160]
  unsigned short* knope = (unsigned short*)(ws + 70 * MB);  //  8 MB [S][2048]
  unsigned short* vt    = (unsigned short*)(ws + 78 * MB);  // 16 MB [D][S]
  unsigned short* cq    = cqkv;                             // [S][.] stride NA
  unsigned short* ckv   = cqkv + P;                         // stride NA
  unsigned short* krope = cqkv + 2 * P;                     // stride NA

  const dim3 tb(32, 8);
  cvt_f32_bf16<<<(S * D / 4 + 255) / 256, 256, 0, stream>>>(x, xb, (long)S * D);

  // GEMM A: x @ [W_DQ | W_DKV | W_Kr]  -> cqkv [S][4160]
  transpose_cvt<<<dim3(P / 32, D / 32), tb, 0, stream>>>(W_DQ, wt, D, P);
  transpose_cvt<<<dim3(P / 32, D / 32), tb, 0, stream>>>(W_DKV, wt + (long)P * D, D, P);
  transpose_cvt<<<dim3(2, D / 32), tb, 0, stream>>>(W_Kr, wt + (long)2 * P * D, D, 64);
  gemm_bt<1, 0, 0><<<dim3((NA + 127) / 128, S / 128), 256, 0, stream>>>(
      xb, wt, cqkv, nullptr, nullptr, S, NA, D, D, D, NA, 0, 0);

  // GEMM B: c_kv @ [W_UK | W_UV] -> knope [S][2048] + vt [D][S] (split epilogue)
  transpose_cvt<<<dim3(P / 32, P / 32), tb, 0, stream>>>(W_UK, wt, P, P);
  transpose_cvt<<<dim3(D / 32, P / 32), tb, 0, stream>>>(W_UV, wt + (long)P * P, P, D);
  gemm_bt<1, 1, 0><<<dim3((P + D) / 128, S / 128), 256, 0, stream>>>(
      ckv, wt, knope, vt, nullptr, S, P + D, P, NA, P, P, P, S);

  // GEMM C: c_q @ W_UQ -> q [S][D]
  transpose_cvt<<<dim3(D / 32, P / 32), tb, 0, stream>>>(W_UQ, wt, P, D);
  gemm_bt<1, 0, 0><<<dim3(D / 128, S / 128), 256, 0, stream>>>(
      cq, wt, qb, nullptr, nullptr, S, D, P, NA, P, D, 0, 0);

  rope_q_kernel<<<(S * 32 * 32 + 255) / 256, 256, 0, stream>>>(qb, past, S);
  rope_k_kernel<<<(S * 32 + 255) / 256, 256, 0, stream>>>(krope, past, S, NA);

  attn_kernel<<<dim3(S / 128, 32), 256, 0, stream>>>(qb, knope, krope, vt, xb, S, NA);

  // GEMM D: attn_out @ W_O + b_O -> out (fp32)
  transpose_cvt<<<dim3(D / 32, D / 32), tb, 0, stream>>>(W_O, wt, D, D);
  gemm_bt<0, 0, 1><<<dim3(D / 128, S / 128), 256, 0, stream>>>(
      xb, wt, out, nullptr, b_O, S, D, D, D, D, D, 0, 0);
}

// Round 2
// 692.833 us; speedup vs baseline: 1.0302x; 1.0302x over previous
//
#include <hip/hip_runtime.h>
#include <math.h>

typedef __attribute__((ext_vector_type(8))) __bf16 bf16x8;
typedef __attribute__((ext_vector_type(4))) float fx4;

__device__ __forceinline__ unsigned short f2bf(float f) {
  union { float f; unsigned int u; } v; v.f = f;
  unsigned int r = v.u + 0x7fffu + ((v.u >> 16) & 1u);
  return (unsigned short)(r >> 16);
}
__device__ __forceinline__ float bf2f(unsigned short b) {
  union { unsigned int u; float f; } v; v.u = ((unsigned int)b) << 16;
  return v.f;
}

// async global->LDS, 16B per lane. LDS dest must be wave-uniform base + lane*16;
// every call site's LDS expression reduces to (16*tid + uniform).
__device__ __forceinline__ void gll16(const unsigned short* g, unsigned short* l) {
  __builtin_amdgcn_global_load_lds(
      (const __attribute__((address_space(1))) unsigned int*)g,
      (__attribute__((address_space(3))) unsigned int*)l, 16, 0, 0);
}

// counted vmem wait + compiler fences (T4: never drain vmcnt to 0 in the loop)
#define WAITV8 asm volatile("s_waitcnt vmcnt(8)" ::: "memory")
#define WAITV0 asm volatile("s_waitcnt vmcnt(0)" ::: "memory")
#define CFENCE asm volatile("" ::: "memory")

// ---------------- fp32 -> bf16 elementwise ----------------
__global__ void cvt_f32_bf16(const float* __restrict__ in, unsigned short* __restrict__ out, long n) {
  long i = ((long)blockIdx.x * blockDim.x + threadIdx.x) * 4;
  if (i + 3 >= n) {
    for (long j = i; j < n; j++) out[j] = f2bf(in[j]);
    return;
  }
  float4 v = *reinterpret_cast<const float4*>(in + i);
  ushort4 o;
  o.x = f2bf(v.x); o.y = f2bf(v.y); o.z = f2bf(v.z); o.w = f2bf(v.w);
  *reinterpret_cast<ushort4*>(out + i) = o;
}

// ---------------- transpose + convert: fp32 [R][C] -> bf16 [C][R] ----------------
__global__ void transpose_cvt(const float* __restrict__ in, unsigned short* __restrict__ out,
                              int R, int C) {
  __shared__ float tile[32][33];
  const int c0 = blockIdx.x * 32, r0 = blockIdx.y * 32;
  const int tx = threadIdx.x, ty = threadIdx.y;  // block (32,8)
#pragma unroll
  for (int k = 0; k < 32; k += 8) {
    int r = r0 + ty + k, c = c0 + tx;
    tile[ty + k][tx] = (r < R && c < C) ? in[(long)r * C + c] : 0.f;
  }
  __syncthreads();
#pragma unroll
  for (int k = 0; k < 32; k += 8) {
    int orow = c0 + ty + k;
    int oc = r0 + tx;
    if (orow < C && oc < R) out[(long)orow * R + oc] = f2bf(tile[tx][ty + k]);
  }
}

// ---------------- bf16 MFMA GEMM: C[M][N] = A[M][K] * Bt[N][K]^T ----------------
// 128x128 tile, BK=64, gll16 staging with XOR chunk swizzle (LDS slot c of
// row r holds global chunk c^(r&7)). Double-buffered pipeline with COUNTED
// vmcnt (T3+T4): per K-step issue next tile's 8 gll16, then s_waitcnt
// vmcnt(8) (current tile's loads landed, next tile's stay in flight),
// s_barrier, compute, s_barrier (WAR). Raw s_barrier — NOT __syncthreads,
// whose implicit vmcnt(0) would drain the prefetch (round-1 regression).
// K must be a multiple of 128 (all call sites: 2048/4096).
// SPLIT: cols < splitN -> C0 [m][n] bf16, cols >= splitN -> C1 transposed
// [n-splitN][m] bf16.
template <int OUT_BF16, int SPLIT, int BIAS>
__global__ __launch_bounds__(256) void gemm_bt(
    const unsigned short* __restrict__ A,   // [M][*lda] bf16
    const unsigned short* __restrict__ Bt,  // [N][*ldb] bf16
    void* __restrict__ C0, void* __restrict__ C1,
    const float* __restrict__ bias,
    int M, int N, int K, int lda, int ldb, int ldc0, int splitN, int ldc1) {
  __shared__ unsigned short As[2][128 * 64];
  __shared__ unsigned short Bs[2][128 * 64];

  const int tid = threadIdx.x;
  const int bn = blockIdx.x * 128;
  const int bm = blockIdx.y * 128;
  const int wave = tid >> 6;
  const int lane = tid & 63;
  const int wm = (wave >> 1) * 64;
  const int wn = (wave & 1) * 64;
  const int lrow = lane & 15;
  const int quad = lane >> 4;

  fx4 acc[4][4];
  const fx4 zero = {0.f, 0.f, 0.f, 0.f};
#pragma unroll
  for (int i = 0; i < 4; i++)
#pragma unroll
    for (int j = 0; j < 4; j++) acc[i][j] = zero;

  const int srow = tid >> 3;                      // 0..31 (LDS row base; +32p)
  const int sw = ((tid & 7) ^ (srow & 7)) * 8;    // swizzled global k-offset

  const unsigned short* ap[4];
  const unsigned short* bp[4];
  int soff[4];                                    // LDS short-offset per p
#pragma unroll
  for (int p = 0; p < 4; p++) {
    const int row = srow + 32 * p;
    ap[p] = A + (long)(bm + row) * lda + sw;
    int nb = bn + row; if (nb > N - 1) nb = N - 1;  // clamp partial-N (epilogue guards)
    bp[p] = Bt + (long)nb * ldb + sw;
    soff[p] = row * 64 + (tid & 7) * 8;
  }

  auto stage = [&](int buf, int k0) {
#pragma unroll
    for (int p = 0; p < 4; p++) gll16(ap[p] + k0, &As[buf][soff[p]]);
#pragma unroll
    for (int p = 0; p < 4; p++) gll16(bp[p] + k0, &Bs[buf][soff[p]]);
  };

  auto compute = [&](int buf) {
#pragma unroll
    for (int kd = 0; kd < 2; kd++) {
      const int co = ((kd * 4 + quad) ^ (lrow & 7)) * 8;  // un-swizzled chunk
      bf16x8 af[4], bfr[4];
#pragma unroll
      for (int i = 0; i < 4; i++)
        af[i] = *reinterpret_cast<const bf16x8*>(&As[buf][(wm + i * 16 + lrow) * 64 + co]);
#pragma unroll
      for (int j = 0; j < 4; j++)
        bfr[j] = *reinterpret_cast<const bf16x8*>(&Bs[buf][(wn + j * 16 + lrow) * 64 + co]);
#pragma unroll
      for (int i = 0; i < 4; i++)
#pragma unroll
        for (int j = 0; j < 4; j++)
          acc[i][j] = __builtin_amdgcn_mfma_f32_16x16x32_bf16(af[i], bfr[j], acc[i][j], 0, 0, 0);
    }
  };

  // prologue: tile 0 -> buf0 (8 loads in flight)
  stage(0, 0);
  const int NT = K >> 6;  // # of 64-wide K tiles; even at all call sites

  for (int t = 0; t + 2 < NT; t += 2) {
    stage(1, (t + 1) << 6);   // prefetch t+1 (outstanding <= 16)
    WAITV8;                   // tile t landed; tile t+1 stays in flight
    __builtin_amdgcn_s_barrier();
    CFENCE;
    compute(0);
    CFENCE;
    __builtin_amdgcn_s_barrier();  // WAR: all waves done reading buf0

    stage(0, (t + 2) << 6);   // prefetch t+2 into buf0
    WAITV8;                   // tile t+1 landed
    __builtin_amdgcn_s_barrier();
    CFENCE;
    compute(1);
    CFENCE;
    __builtin_amdgcn_s_barrier();  // WAR: all waves done reading buf1
  }

  // epilogue: tiles NT-2 (in buf0, loads in flight) and NT-1
  stage(1, (NT - 1) << 6);
  WAITV8;
  __builtin_amdgcn_s_barrier();
  CFENCE;
  compute(0);
  CFENCE;
  WAITV0;                     // last tile's loads landed
  __builtin_amdgcn_s_barrier();
  CFENCE;
  compute(1);

  // C row = quad*4+reg, col = lane&15
#pragma unroll
  for (int i = 0; i < 4; i++) {
#pragma unroll
    for (int j = 0; j < 4; j++) {
      const int gn = bn + wn + j * 16 + lrow;
      if (gn < N) {
        const int gmb = bm + wm + i * 16 + quad * 4;
        if (SPLIT && gn >= splitN) {
#pragma unroll
          for (int r = 0; r < 4; r++)
            ((unsigned short*)C1)[(long)(gn - splitN) * ldc1 + gmb + r] = f2bf(acc[i][j][r]);
        } else {
          float bv = 0.f;
          if (BIAS) bv = bias[gn];
#pragma unroll
          for (int r = 0; r < 4; r++) {
            float v = acc[i][j][r] + bv;
            long idx = (long)(gmb + r) * ldc0 + gn;
            if (OUT_BF16) ((unsigned short*)C0)[idx] = f2bf(v);
            else ((float*)C0)[idx] = v;
          }
        }
      }
    }
  }
}

// ---------------- RoPE ----------------
__global__ void rope_q_kernel(unsigned short* __restrict__ q, const int* __restrict__ past_p, int S) {
  int idx = blockIdx.x * blockDim.x + threadIdx.x;
  if (idx >= S * 32 * 32) return;
  int i = idx & 31, h = (idx >> 5) & 31, s = idx >> 10;
  int past = past_p[0];
  float f = powf(10000.0f, -(float)i * (1.0f / 64.0f));
  float ang = (float)(past + s) * f;
  float sn, cs;
  sincosf(ang, &sn, &cs);
  unsigned short* base = q + (long)s * 4096 + h * 128 + 64;
  float x1 = bf2f(base[i]), x2 = bf2f(base[i + 32]);
  base[i] = f2bf(x1 * cs - x2 * sn);
  base[i + 32] = f2bf(x2 * cs + x1 * sn);
}

__global__ void rope_k_kernel(unsigned short* __restrict__ kr, const int* __restrict__ past_p,
                              int S, int ldk) {
  int idx = blockIdx.x * blockDim.x + threadIdx.x;
  if (idx >= S * 32) return;
  int i = idx & 31, s = idx >> 5;
  int past = past_p[0];
  float f = powf(10000.0f, -(float)i * (1.0f / 64.0f));
  float ang = (float)(past + s) * f;
  float sn, cs;
  sincosf(ang, &sn, &cs);
  unsigned short* base = kr + (long)s * ldk;
  float x1 = bf2f(base[i]), x2 = bf2f(base[i + 32]);
  base[i] = f2bf(x1 * cs - x2 * sn);
  base[i + 32] = f2bf(x2 * cs + x1 * sn);
}

// ---------------- flash attention (no-max softmax, deferred l-reduction) ----
// block = 1 head x 128 q-rows; 4 waves x 32 q-rows; 64-key tiles.
// Ks/Vs staged via gll16 with XOR chunk swizzle to kill the stride-degenerate
// bank conflicts.
__global__ __launch_bounds__(256, 2) void attn_kernel(
    const unsigned short* __restrict__ Q,   // [S][4096] bf16 (rope applied)
    const unsigned short* __restrict__ Kn,  // [S][2048] bf16
    const unsigned short* __restrict__ Kr,  // [S][ldkr] bf16 (rope applied)
    const unsigned short* __restrict__ Vt,  // [4096][S] bf16 (per-head transposed)
    unsigned short* __restrict__ O,         // [S][4096] bf16
    int S, int ldkr) {
  const int h = blockIdx.y;
  const int sb = blockIdx.x * 128;
  const int tid = threadIdx.x;
  const int wave = tid >> 6;
  const int lane = tid & 63;
  const int lrow = lane & 15;
  const int quad = lane >> 4;

  __shared__ unsigned short Ks[64 * 128];   // [key][d], chunk-swizzled by key&15
  __shared__ unsigned short Vs[128 * 64];   // [dv][key], chunk-swizzled by dv&7
  __shared__ unsigned short Ps[4][32 * 72]; // per-wave P tile

  const int qr0 = sb + wave * 32;

  bf16x8 qf[2][4];
#pragma unroll
  for (int qi = 0; qi < 2; qi++)
#pragma unroll
    for (int kd = 0; kd < 4; kd++)
      qf[qi][kd] = *reinterpret_cast<const bf16x8*>(
          Q + (long)(qr0 + qi * 16 + lrow) * 4096 + h * 128 + kd * 32 + quad * 8);

  fx4 accO[2][8];
  const fx4 zero = {0.f, 0.f, 0.f, 0.f};
#pragma unroll
  for (int qi = 0; qi < 2; qi++)
#pragma unroll
    for (int t = 0; t < 8; t++) accO[qi][t] = zero;
  float lsum[2][4] = {{0.f, 0.f, 0.f, 0.f}, {0.f, 0.f, 0.f, 0.f}};
  const float scale = 0.08838834764831845f;  // 1/sqrt(128)

  // K staging: LDS row kkey+16p, slot chunk tid&15 holds global chunk cgk
  const int kkey = tid >> 4;                     // 0..15
  const int cgk = ((tid & 15) ^ kkey) * 8;       // swizzled global d-offset 0..120
  // V staging: LDS row vdv+32p, slot chunk tid&7 holds global chunk cgv
  const int vdv = tid >> 3;                      // 0..31
  const int cgv = ((tid & 7) ^ (vdv & 7)) * 8;   // swizzled global key-offset 0..56

  for (int kb = 0; kb < S; kb += 64) {
    __syncthreads();
#pragma unroll
    for (int p = 0; p < 4; p++) {
      const int key = kb + kkey + 16 * p;
      const unsigned short* gn_ = Kn + (long)key * 2048 + h * 64 + cgk;
      const unsigned short* gr_ = Kr + (long)key * ldkr + (cgk - 64);
      gll16(cgk < 64 ? gn_ : gr_, &Ks[(kkey + 16 * p) * 128 + (tid & 15) * 8]);
    }
#pragma unroll
    for (int p = 0; p < 4; p++)
      gll16(Vt + (long)(h * 128 + vdv + 32 * p) * S + kb + cgv,
            &Vs[(vdv + 32 * p) * 64 + (tid & 7) * 8]);
    __syncthreads();

    // QK^T: 2 q-subtiles x 64 keys (Ks chunk un-swizzle: c=(kd*4+quad)^lrow)
    fx4 c[2][4];
#pragma unroll
    for (int qi = 0; qi < 2; qi++)
#pragma unroll
      for (int ks2 = 0; ks2 < 4; ks2++) c[qi][ks2] = zero;
#pragma unroll
    for (int ks2 = 0; ks2 < 4; ks2++) {
#pragma unroll
      for (int kd = 0; kd < 4; kd++) {
        bf16x8 kf = *reinterpret_cast<const bf16x8*>(
            &Ks[(ks2 * 16 + lrow) * 128 + (((kd * 4 + quad) ^ lrow) * 8)]);
        c[0][ks2] = __builtin_amdgcn_mfma_f32_16x16x32_bf16(qf[0][kd], kf, c[0][ks2], 0, 0, 0);
        c[1][ks2] = __builtin_amdgcn_mfma_f32_16x16x32_bf16(qf[1][kd], kf, c[1][ks2], 0, 0, 0);
      }
    }

    // exp + per-lane l accumulation + P store (C-layout row=quad*4+r, col=16*ks2+lrow)
#pragma unroll
    for (int qi = 0; qi < 2; qi++) {
#pragma unroll
      for (int ks2 = 0; ks2 < 4; ks2++) {
#pragma unroll
        for (int r = 0; r < 4; r++) {
          float p = __expf(c[qi][ks2][r] * scale);
          lsum[qi][r] += p;
          Ps[wave][(qi * 16 + quad * 4 + r) * 72 + ks2 * 16 + lrow] = f2bf(p);
        }
      }
    }
    __threadfence_block();  // order cross-lane LDS write->read within the wave

    // PV: P (A-layout) x V^T (B-layout; Vs chunk un-swizzle c=(kc*4+quad)^(lrow&7))
#pragma unroll
    for (int kc = 0; kc < 2; kc++) {
      bf16x8 pf0 = *reinterpret_cast<const bf16x8*>(&Ps[wave][lrow * 72 + kc * 32 + quad * 8]);
      bf16x8 pf1 = *reinterpret_cast<const bf16x8*>(&Ps[wave][(16 + lrow) * 72 + kc * 32 + quad * 8]);
      const int vco = (((kc * 4 + quad) ^ (lrow & 7)) * 8);
#pragma unroll
      for (int t = 0; t < 8; t++) {
        bf16x8 vf = *reinterpret_cast<const bf16x8*>(&Vs[(t * 16 + lrow) * 64 + vco]);
        accO[0][t] = __builtin_amdgcn_mfma_f32_16x16x32_bf16(pf0, vf, accO[0][t], 0, 0, 0);
        accO[1][t] = __builtin_amdgcn_mfma_f32_16x16x32_bf16(pf1, vf, accO[1][t], 0, 0, 0);
      }
    }
  }

  // one-time l reduction across the 16 lanes of each quad, then normalize+store
  float linv[2][4];
#pragma unroll
  for (int qi = 0; qi < 2; qi++)
#pragma unroll
    for (int r = 0; r < 4; r++) {
      float l = lsum[qi][r];
#pragma unroll
      for (int off = 8; off; off >>= 1) l += __shfl_xor(l, off, 16);
      linv[qi][r] = 1.0f / l;
    }
#pragma unroll
  for (int qi = 0; qi < 2; qi++)
#pragma unroll
    for (int t = 0; t < 8; t++)
#pragma unroll
      for (int r = 0; r < 4; r++) {
        float v = accO[qi][t][r] * linv[qi][r];
        int row = qr0 + qi * 16 + quad * 4 + r;
        O[(long)row * 4096 + h * 128 + t * 16 + lrow] = f2bf(v);
      }
}

// ---------------- launch ----------------
extern "C" void kernel_launch(void* const* d_in, const int* in_sizes, int n_in,
                              void* d_out, int out_size, void* d_ws, size_t ws_size,
                              hipStream_t stream) {
  (void)in_sizes; (void)n_in; (void)out_size; (void)ws_size;
  const float* x     = (const float*)d_in[0];
  const float* W_DQ  = (const float*)d_in[1];
  const float* W_UQ  = (const float*)d_in[2];
  const float* W_DKV = (const float*)d_in[3];
  const float* W_UK  = (const float*)d_in[4];
  const float* W_UV  = (const float*)d_in[5];
  const float* W_Kr  = (const float*)d_in[6];
  const float* W_O   = (const float*)d_in[7];
  const float* b_O   = (const float*)d_in[8];
  const int* past    = (const int*)d_in[9];
  float* out = (float*)d_out;

  const int S = 2048, D = 4096, P = 2048;
  const int NA = P + P + 64;  // 4160: fused [W_DQ|W_DKV|W_Kr] output width
  char* ws = (char*)d_ws;
  const long MB = 1024 * 1024;
  unsigned short* xb    = (unsigned short*)(ws);            // 16 MB [S][D] x / attn-out
  unsigned short* wt    = (unsigned short*)(ws + 16 * MB);  // ~34 MB transposed weights (reused)
  unsigned short* qb    = (unsigned short*)(ws + 36 * MB);  // 16 MB q
  unsigned short* cqkv  = (unsigned short*)(ws + 52 * MB);  // 17.1 MB [S][4160]
  unsigned short* knope = (unsigned short*)(ws + 70 * MB);  //  8 MB [S][2048]
  unsigned short* vt    = (unsigned short*)(ws + 78 * MB);  // 16 MB [D][S]
  unsigned short* cq    = cqkv;                             // [S][.] stride NA
  unsigned short* ckv   = cqkv + P;                         // stride NA
  unsigned short* krope = cqkv + 2 * P;                     // stride NA

  const dim3 tb(32, 8);
  cvt_f32_bf16<<<(S * D / 4 + 255) / 256, 256, 0, stream>>>(x, xb, (long)S * D);

  // GEMM A: x @ [W_DQ | W_DKV | W_Kr]  -> cqkv [S][4160]
  transpose_cvt<<<dim3(P / 32, D / 32), tb, 0, stream>>>(W_DQ, wt, D, P);
  transpose_cvt<<<dim3(P / 32, D / 32), tb, 0, stream>>>(W_DKV, wt + (long)P * D, D, P);
  transpose_cvt<<<dim3(2, D / 32), tb, 0, stream>>>(W_Kr, wt + (long)2 * P * D, D, 64);
  gemm_bt<1, 0, 0><<<dim3((NA + 127) / 128, S / 128), 256, 0, stream>>>(
      xb, wt, cqkv, nullptr, nullptr, S, NA, D, D, D, NA, 0, 0);

  // GEMM B: c_kv @ [W_UK | W_UV] -> knope [S][2048] + vt [D][S] (split epilogue)
  transpose_cvt<<<dim3(P / 32, P / 32), tb, 0, stream>>>(W_UK, wt, P, P);
  transpose_cvt<<<dim3(D / 32, P / 32), tb, 0, stream>>>(W_UV, wt + (long)P * P, P, D);
  gemm_bt<1, 1, 0><<<dim3((P + D) / 128, S / 128), 256, 0, stream>>>(
      ckv, wt, knope, vt, nullptr, S, P + D, P, NA, P, P, P, S);

  // GEMM C: c_q @ W_UQ -> q [S][D]
  transpose_cvt<<<dim3(D / 32, P / 32), tb, 0, stream>>>(W_UQ, wt, P, D);
  gemm_bt<1, 0, 0><<<dim3(D / 128, S / 128), 256, 0, stream>>>(
      cq, wt, qb, nullptr, nullptr, S, D, P, NA, P, D, 0, 0);

  rope_q_kernel<<<(S * 32 * 32 + 255) / 256, 256, 0, stream>>>(qb, past, S);
  rope_k_kernel<<<(S * 32 + 255) / 256, 256, 0, stream>>>(krope, past, S, NA);

  attn_kernel<<<dim3(S / 128, 32), 256, 0, stream>>>(qb, knope, krope, vt, xb, S, NA);

  // GEMM D: attn_out @ W_O + b_O -> out (fp32)
  transpose_cvt<<<dim3(D / 32, D / 32), tb, 0, stream>>>(W_O, wt, D, D);
  gemm_bt<0, 0, 1><<<dim3(D / 128, S / 128), 256, 0, stream>>>(
      xb, wt, out, nullptr, b_O, S, D, D, D, D, D, 0, 0);
}

// Round 4
// 682.108 us; speedup vs baseline: 1.0464x; 1.0157x over previous
//
#include <hip/hip_runtime.h>
#include <math.h>

typedef __attribute__((ext_vector_type(8))) __bf16 bf16x8;
typedef __attribute__((ext_vector_type(4))) float fx4;

__device__ __forceinline__ unsigned short f2bf(float f) {
  union { float f; unsigned int u; } v; v.f = f;
  unsigned int r = v.u + 0x7fffu + ((v.u >> 16) & 1u);
  return (unsigned short)(r >> 16);
}
__device__ __forceinline__ float bf2f(unsigned short b) {
  union { unsigned int u; float f; } v; v.u = ((unsigned int)b) << 16;
  return v.f;
}

// async global->LDS, 16B per lane. LDS dest must be wave-uniform base + lane*16;
// every call site's LDS expression reduces to (16*tid + uniform).
__device__ __forceinline__ void gll16(const unsigned short* g, unsigned short* l) {
  __builtin_amdgcn_global_load_lds(
      (const __attribute__((address_space(1))) unsigned int*)g,
      (__attribute__((address_space(3))) unsigned int*)l, 16, 0, 0);
}

// ---------------- fp32 -> bf16 elementwise ----------------
__global__ void cvt_f32_bf16(const float* __restrict__ in, unsigned short* __restrict__ out, long n) {
  long i = ((long)blockIdx.x * blockDim.x + threadIdx.x) * 4;
  if (i + 3 >= n) {
    for (long j = i; j < n; j++) out[j] = f2bf(in[j]);
    return;
  }
  float4 v = *reinterpret_cast<const float4*>(in + i);
  ushort4 o;
  o.x = f2bf(v.x); o.y = f2bf(v.y); o.z = f2bf(v.z); o.w = f2bf(v.w);
  *reinterpret_cast<ushort4*>(out + i) = o;
}

// ---------------- transpose + convert: fp32 [R][C] -> bf16 [C][R] ----------------
__global__ void transpose_cvt(const float* __restrict__ in, unsigned short* __restrict__ out,
                              int R, int C) {
  __shared__ float tile[32][33];
  const int c0 = blockIdx.x * 32, r0 = blockIdx.y * 32;
  const int tx = threadIdx.x, ty = threadIdx.y;  // block (32,8)
#pragma unroll
  for (int k = 0; k < 32; k += 8) {
    int r = r0 + ty + k, c = c0 + tx;
    tile[ty + k][tx] = (r < R && c < C) ? in[(long)r * C + c] : 0.f;
  }
  __syncthreads();
#pragma unroll
  for (int k = 0; k < 32; k += 8) {
    int orow = c0 + ty + k;
    int oc = r0 + tx;
    if (orow < C && oc < R) out[(long)orow * R + oc] = f2bf(tile[tx][ty + k]);
  }
}

// ---------------- bf16 MFMA GEMM: C[M][N] = A[M][K] * Bt[N][K]^T ----------------
// 128x128 tile, BK=128 (64 MFMA/wave per barrier-pair — amortizes the
// vmcnt(0) drain; grid caps occupancy at 2 blocks/CU so the 64 KB LDS does
// not cost residency). Serial stage->drain->compute structure (both
// pipelining attempts measured slower). gll16 staging with 16-chunk XOR
// swizzle (LDS slot c of row r holds global chunk c^(r&15)) — same pattern
// as attn K-staging, measured 0 bank conflicts.
// K must be a multiple of 128 (all call sites: 2048/4096).
// SPLIT: cols < splitN -> C0 [m][n] bf16, cols >= splitN -> C1 transposed
// [n-splitN][m] bf16.
template <int OUT_BF16, int SPLIT, int BIAS>
__global__ __launch_bounds__(256) void gemm_bt(
    const unsigned short* __restrict__ A,   // [M][*lda] bf16
    const unsigned short* __restrict__ Bt,  // [N][*ldb] bf16
    void* __restrict__ C0, void* __restrict__ C1,
    const float* __restrict__ bias,
    int M, int N, int K, int lda, int ldb, int ldc0, int splitN, int ldc1) {
  __shared__ unsigned short As[128 * 128];
  __shared__ unsigned short Bs[128 * 128];

  const int tid = threadIdx.x;
  const int bn = blockIdx.x * 128;
  const int bm = blockIdx.y * 128;
  const int wave = tid >> 6;
  const int lane = tid & 63;
  const int wm = (wave >> 1) * 64;
  const int wn = (wave & 1) * 64;
  const int lrow = lane & 15;
  const int quad = lane >> 4;

  fx4 acc[4][4];
  const fx4 zero = {0.f, 0.f, 0.f, 0.f};
#pragma unroll
  for (int i = 0; i < 4; i++)
#pragma unroll
    for (int j = 0; j < 4; j++) acc[i][j] = zero;

  // staging: 16 lanes per row (256 B), row = (tid>>4) + 16p, slot chunk tid&15
  const int srow = tid >> 4;                      // 0..15 (row base; +16p)
  const int sw = ((tid & 15) ^ srow) * 8;         // swizzled global k-offset
                                                  // (row&15 == srow for all p)
  const unsigned short* ap[8];
  const unsigned short* bp[8];
  int soff[8];                                    // LDS short-offset per p
#pragma unroll
  for (int p = 0; p < 8; p++) {
    const int row = srow + 16 * p;
    ap[p] = A + (long)(bm + row) * lda + sw;
    int nb = bn + row; if (nb > N - 1) nb = N - 1;  // clamp partial-N (epilogue guards)
    bp[p] = Bt + (long)nb * ldb + sw;
    soff[p] = row * 128 + (tid & 15) * 8;
  }

  for (int k0 = 0; k0 < K; k0 += 128) {
    __syncthreads();
#pragma unroll
    for (int p = 0; p < 8; p++) gll16(ap[p] + k0, &As[soff[p]]);
#pragma unroll
    for (int p = 0; p < 8; p++) gll16(bp[p] + k0, &Bs[soff[p]]);
    __syncthreads();

#pragma unroll
    for (int kd = 0; kd < 4; kd++) {
      const int co = ((kd * 4 + quad) ^ lrow) * 8;  // un-swizzled chunk (16-chunk XOR)
      bf16x8 af[4], bfr[4];
#pragma unroll
      for (int i = 0; i < 4; i++)
        af[i] = *reinterpret_cast<const bf16x8*>(&As[(wm + i * 16 + lrow) * 128 + co]);
#pragma unroll
      for (int j = 0; j < 4; j++)
        bfr[j] = *reinterpret_cast<const bf16x8*>(&Bs[(wn + j * 16 + lrow) * 128 + co]);
#pragma unroll
      for (int i = 0; i < 4; i++)
#pragma unroll
        for (int j = 0; j < 4; j++)
          acc[i][j] = __builtin_amdgcn_mfma_f32_16x16x32_bf16(af[i], bfr[j], acc[i][j], 0, 0, 0);
    }
  }

  // C row = quad*4+reg, col = lane&15
#pragma unroll
  for (int i = 0; i < 4; i++) {
#pragma unroll
    for (int j = 0; j < 4; j++) {
      const int gn = bn + wn + j * 16 + lrow;
      if (gn < N) {
        const int gmb = bm + wm + i * 16 + quad * 4;
        if (SPLIT && gn >= splitN) {
#pragma unroll
          for (int r = 0; r < 4; r++)
            ((unsigned short*)C1)[(long)(gn - splitN) * ldc1 + gmb + r] = f2bf(acc[i][j][r]);
        } else {
          float bv = 0.f;
          if (BIAS) bv = bias[gn];
#pragma unroll
          for (int r = 0; r < 4; r++) {
            float v = acc[i][j][r] + bv;
            long idx = (long)(gmb + r) * ldc0 + gn;
            if (OUT_BF16) ((unsigned short*)C0)[idx] = f2bf(v);
            else ((float*)C0)[idx] = v;
          }
        }
      }
    }
  }
}

// ---------------- RoPE ----------------
__global__ void rope_q_kernel(unsigned short* __restrict__ q, const int* __restrict__ past_p, int S) {
  int idx = blockIdx.x * blockDim.x + threadIdx.x;
  if (idx >= S * 32 * 32) return;
  int i = idx & 31, h = (idx >> 5) & 31, s = idx >> 10;
  int past = past_p[0];
  float f = powf(10000.0f, -(float)i * (1.0f / 64.0f));
  float ang = (float)(past + s) * f;
  float sn, cs;
  sincosf(ang, &sn, &cs);
  unsigned short* base = q + (long)s * 4096 + h * 128 + 64;
  float x1 = bf2f(base[i]), x2 = bf2f(base[i + 32]);
  base[i] = f2bf(x1 * cs - x2 * sn);
  base[i + 32] = f2bf(x2 * cs + x1 * sn);
}

__global__ void rope_k_kernel(unsigned short* __restrict__ kr, const int* __restrict__ past_p,
                              int S, int ldk) {
  int idx = blockIdx.x * blockDim.x + threadIdx.x;
  if (idx >= S * 32) return;
  int i = idx & 31, s = idx >> 5;
  int past = past_p[0];
  float f = powf(10000.0f, -(float)i * (1.0f / 64.0f));
  float ang = (float)(past + s) * f;
  float sn, cs;
  sincosf(ang, &sn, &cs);
  unsigned short* base = kr + (long)s * ldk;
  float x1 = bf2f(base[i]), x2 = bf2f(base[i + 32]);
  base[i] = f2bf(x1 * cs - x2 * sn);
  base[i + 32] = f2bf(x2 * cs + x1 * sn);
}

// ---------------- flash attention (no-max softmax, deferred l-reduction) ----
// block = 1 head x 128 q-rows; 4 waves x 32 q-rows; 64-key tiles.
// Ks/Vs staged via gll16 with XOR chunk swizzle to kill the stride-degenerate
// bank conflicts.
__global__ __launch_bounds__(256, 2) void attn_kernel(
    const unsigned short* __restrict__ Q,   // [S][4096] bf16 (rope applied)
    const unsigned short* __restrict__ Kn,  // [S][2048] bf16
    const unsigned short* __restrict__ Kr,  // [S][ldkr] bf16 (rope applied)
    const unsigned short* __restrict__ Vt,  // [4096][S] bf16 (per-head transposed)
    unsigned short* __restrict__ O,         // [S][4096] bf16
    int S, int ldkr) {
  const int h = blockIdx.y;
  const int sb = blockIdx.x * 128;
  const int tid = threadIdx.x;
  const int wave = tid >> 6;
  const int lane = tid & 63;
  const int lrow = lane & 15;
  const int quad = lane >> 4;

  __shared__ unsigned short Ks[64 * 128];   // [key][d], chunk-swizzled by key&15
  __shared__ unsigned short Vs[128 * 64];   // [dv][key], chunk-swizzled by dv&7
  __shared__ unsigned short Ps[4][32 * 72]; // per-wave P tile

  const int qr0 = sb + wave * 32;

  bf16x8 qf[2][4];
#pragma unroll
  for (int qi = 0; qi < 2; qi++)
#pragma unroll
    for (int kd = 0; kd < 4; kd++)
      qf[qi][kd] = *reinterpret_cast<const bf16x8*>(
          Q + (long)(qr0 + qi * 16 + lrow) * 4096 + h * 128 + kd * 32 + quad * 8);

  fx4 accO[2][8];
  const fx4 zero = {0.f, 0.f, 0.f, 0.f};
#pragma unroll
  for (int qi = 0; qi < 2; qi++)
#pragma unroll
    for (int t = 0; t < 8; t++) accO[qi][t] = zero;
  float lsum[2][4] = {{0.f, 0.f, 0.f, 0.f}, {0.f, 0.f, 0.f, 0.f}};
  const float scale = 0.08838834764831845f;  // 1/sqrt(128)

  // K staging: LDS row kkey+16p, slot chunk tid&15 holds global chunk cgk
  const int kkey = tid >> 4;                     // 0..15
  const int cgk = ((tid & 15) ^ kkey) * 8;       // swizzled global d-offset 0..120
  // V staging: LDS row vdv+32p, slot chunk tid&7 holds global chunk cgv
  const int vdv = tid >> 3;                      // 0..31
  const int cgv = ((tid & 7) ^ (vdv & 7)) * 8;   // swizzled global key-offset 0..56

  for (int kb = 0; kb < S; kb += 64) {
    __syncthreads();
#pragma unroll
    for (int p = 0; p < 4; p++) {
      const int key = kb + kkey + 16 * p;
      const unsigned short* gn_ = Kn + (long)key * 2048 + h * 64 + cgk;
      const unsigned short* gr_ = Kr + (long)key * ldkr + (cgk - 64);
      gll16(cgk < 64 ? gn_ : gr_, &Ks[(kkey + 16 * p) * 128 + (tid & 15) * 8]);
    }
#pragma unroll
    for (int p = 0; p < 4; p++)
      gll16(Vt + (long)(h * 128 + vdv + 32 * p) * S + kb + cgv,
            &Vs[(vdv + 32 * p) * 64 + (tid & 7) * 8]);
    __syncthreads();

    // QK^T: 2 q-subtiles x 64 keys (Ks chunk un-swizzle: c=(kd*4+quad)^lrow)
    fx4 c[2][4];
#pragma unroll
    for (int qi = 0; qi < 2; qi++)
#pragma unroll
      for (int ks2 = 0; ks2 < 4; ks2++) c[qi][ks2] = zero;
#pragma unroll
    for (int ks2 = 0; ks2 < 4; ks2++) {
#pragma unroll
      for (int kd = 0; kd < 4; kd++) {
        bf16x8 kf = *reinterpret_cast<const bf16x8*>(
            &Ks[(ks2 * 16 + lrow) * 128 + (((kd * 4 + quad) ^ lrow) * 8)]);
        c[0][ks2] = __builtin_amdgcn_mfma_f32_16x16x32_bf16(qf[0][kd], kf, c[0][ks2], 0, 0, 0);
        c[1][ks2] = __builtin_amdgcn_mfma_f32_16x16x32_bf16(qf[1][kd], kf, c[1][ks2], 0, 0, 0);
      }
    }

    // exp + per-lane l accumulation + P store (C-layout row=quad*4+r, col=16*ks2+lrow)
#pragma unroll
    for (int qi = 0; qi < 2; qi++) {
#pragma unroll
      for (int ks2 = 0; ks2 < 4; ks2++) {
#pragma unroll
        for (int r = 0; r < 4; r++) {
          float p = __expf(c[qi][ks2][r] * scale);
          lsum[qi][r] += p;
          Ps[wave][(qi * 16 + quad * 4 + r) * 72 + ks2 * 16 + lrow] = f2bf(p);
        }
      }
    }
    __threadfence_block();  // order cross-lane LDS write->read within the wave

    // PV: P (A-layout) x V^T (B-layout; Vs chunk un-swizzle c=(kc*4+quad)^(lrow&7))
#pragma unroll
    for (int kc = 0; kc < 2; kc++) {
      bf16x8 pf0 = *reinterpret_cast<const bf16x8*>(&Ps[wave][lrow * 72 + kc * 32 + quad * 8]);
      bf16x8 pf1 = *reinterpret_cast<const bf16x8*>(&Ps[wave][(16 + lrow) * 72 + kc * 32 + quad * 8]);
      const int vco = (((kc * 4 + quad) ^ (lrow & 7)) * 8);
#pragma unroll
      for (int t = 0; t < 8; t++) {
        bf16x8 vf = *reinterpret_cast<const bf16x8*>(&Vs[(t * 16 + lrow) * 64 + vco]);
        accO[0][t] = __builtin_amdgcn_mfma_f32_16x16x32_bf16(pf0, vf, accO[0][t], 0, 0, 0);
        accO[1][t] = __builtin_amdgcn_mfma_f32_16x16x32_bf16(pf1, vf, accO[1][t], 0, 0, 0);
      }
    }
  }

  // one-time l reduction across the 16 lanes of each quad, then normalize+store
  float linv[2][4];
#pragma unroll
  for (int qi = 0; qi < 2; qi++)
#pragma unroll
    for (int r = 0; r < 4; r++) {
      float l = lsum[qi][r];
#pragma unroll
      for (int off = 8; off; off >>= 1) l += __shfl_xor(l, off, 16);
      linv[qi][r] = 1.0f / l;
    }
#pragma unroll
  for (int qi = 0; qi < 2; qi++)
#pragma unroll
    for (int t = 0; t < 8; t++)
#pragma unroll
      for (int r = 0; r < 4; r++) {
        float v = accO[qi][t][r] * linv[qi][r];
        int row = qr0 + qi * 16 + quad * 4 + r;
        O[(long)row * 4096 + h * 128 + t * 16 + lrow] = f2bf(v);
      }
}

// ---------------- launch ----------------
extern "C" void kernel_launch(void* const* d_in, const int* in_sizes, int n_in,
                              void* d_out, int out_size, void* d_ws, size_t ws_size,
                              hipStream_t stream) {
  (void)in_sizes; (void)n_in; (void)out_size; (void)ws_size;
  const float* x     = (const float*)d_in[0];
  const float* W_DQ  = (const float*)d_in[1];
  const float* W_UQ  = (const float*)d_in[2];
  const float* W_DKV = (const float*)d_in[3];
  const float* W_UK  = (const float*)d_in[4];
  const float* W_UV  = (const float*)d_in[5];
  const float* W_Kr  = (const float*)d_in[6];
  const float* W_O   = (const float*)d_in[7];
  const float* b_O   = (const float*)d_in[8];
  const int* past    = (const int*)d_in[9];
  float* out = (float*)d_out;

  const int S = 2048, D = 4096, P = 2048;
  const int NA = P + P + 64;  // 4160: fused [W_DQ|W_DKV|W_Kr] output width
  char* ws = (char*)d_ws;
  const long MB = 1024 * 1024;
  unsigned short* xb    = (unsigned short*)(ws);            // 16 MB [S][D] x / attn-out
  unsigned short* wt    = (unsigned short*)(ws + 16 * MB);  // ~34 MB transposed weights (reused)
  unsigned short* qb    = (unsigned short*)(ws + 36 * MB);  // 16 MB q (GEMM C only reads
                                                            //   wt[0..16MB) = [16,32MB) as B)
  unsigned short* cqkv  = (unsigned short*)(ws + 52 * MB);  // 17.1 MB [S][4160]
  unsigned short* knope = (unsigned short*)(ws + 70 * MB);  //  8 MB [S][2048]
  unsigned short* vt    = (unsigned short*)(ws + 78 * MB);  // 16 MB [D][S]
  unsigned short* cq    = cqkv;                             // [S][.] stride NA
  unsigned short* ckv   = cqkv + P;                         // stride NA
  unsigned short* krope = cqkv + 2 * P;                     // stride NA

  const dim3 tb(32, 8);
  cvt_f32_bf16<<<(S * D / 4 + 255) / 256, 256, 0, stream>>>(x, xb, (long)S * D);

  // GEMM A: x @ [W_DQ | W_DKV | W_Kr]  -> cqkv [S][4160]
  transpose_cvt<<<dim3(P / 32, D / 32), tb, 0, stream>>>(W_DQ, wt, D, P);
  transpose_cvt<<<dim3(P / 32, D / 32), tb, 0, stream>>>(W_DKV, wt + (long)P * D, D, P);
  transpose_cvt<<<dim3(2, D / 32), tb, 0, stream>>>(W_Kr, wt + (long)2 * P * D, D, 64);
  gemm_bt<1, 0, 0><<<dim3((NA + 127) / 128, S / 128), 256, 0, stream>>>(
      xb, wt, cqkv, nullptr, nullptr, S, NA, D, D, D, NA, 0, 0);

  // GEMM B: c_kv @ [W_UK | W_UV] -> knope [S][2048] + vt [D][S] (split epilogue)
  transpose_cvt<<<dim3(P / 32, P / 32), tb, 0, stream>>>(W_UK, wt, P, P);
  transpose_cvt<<<dim3(D / 32, P / 32), tb, 0, stream>>>(W_UV, wt + (long)P * P, P, D);
  gemm_bt<1, 1, 0><<<dim3((P + D) / 128, S / 128), 256, 0, stream>>>(
      ckv, wt, knope, vt, nullptr, S, P + D, P, NA, P, P, P, S);

  // GEMM C: c_q @ W_UQ -> q [S][D]
  transpose_cvt<<<dim3(D / 32, P / 32), tb, 0, stream>>>(W_UQ, wt, P, D);
  gemm_bt<1, 0, 0><<<dim3(D / 128, S / 128), 256, 0, stream>>>(
      cq, wt, qb, nullptr, nullptr, S, D, P, NA, P, D, 0, 0);

  rope_q_kernel<<<(S * 32 * 32 + 255) / 256, 256, 0, stream>>>(qb, past, S);
  rope_k_kernel<<<(S * 32 + 255) / 256, 256, 0, stream>>>(krope, past, S, NA);

  attn_kernel<<<dim3(S / 128, 32), 256, 0, stream>>>(qb, knope, krope, vt, xb, S, NA);

  // GEMM D: attn_out @ W_O + b_O -> out (fp32)
  transpose_cvt<<<dim3(D / 32, D / 32), tb, 0, stream>>>(W_O, wt, D, D);
  gemm_bt<0, 0, 1><<<dim3(D / 128, S / 128), 256, 0, stream>>>(
      xb, wt, out, nullptr, b_O, S, D, D, D, D, D, 0, 0);
}